// Round 21
// baseline (424.430 us; speedup 1.0000x reference)
//
#include <hip/hip_runtime.h>
#include <cstdint>
#include <cstddef>

#define NEG_SLOPE 0.01f

__device__ __forceinline__ float leakyf(float v) { return v > 0.f ? v : NEG_SLOPE * v; }

// ---------------- weight transpose: w[co][ci][k][k] -> wT[ci][k][k][co] ----------------
__global__ void wtrans_k(const float* __restrict__ w, float* __restrict__ wT,
                         int CIN, int COUT, int KK) {
    int idx = blockIdx.x * blockDim.x + threadIdx.x;
    int total = COUT * CIN * KK;
    if (idx >= total) return;
    int co = idx / (CIN * KK);
    int rem = idx % (CIN * KK);
    wT[(size_t)rem * COUT + co] = w[idx];
}

// ---------------- decoder weight transpose: w[ci][co][9] -> wtd[ci][9][co] ----------------
__global__ void wtransD_k(const float* __restrict__ w, float* __restrict__ wtd,
                          int CIN, int COUT) {
    int idx = blockIdx.x * blockDim.x + threadIdx.x;
    int total = CIN * COUT * 9;
    if (idx >= total) return;
    int ci = idx / (COUT * 9);
    int r = idx % (COUT * 9);
    int co = r / 9;
    int t = r % 9;
    wtd[((size_t)ci * 9 + t) * COUT + co] = w[idx];
}

// ---------------- pad input images into zero-bordered buffer [2][3][H+8][W+8] ----------------
__global__ void pad_in_k(const float* __restrict__ x1, const float* __restrict__ x2,
                         float* __restrict__ dst, int C, int H, int W) {
    int idx = blockIdx.x * blockDim.x + threadIdx.x;  // exact grid: 2*C*H*W
    int HW = H * W;
    int img = idx / (C * HW);
    int rem = idx % (C * HW);
    int c = rem / HW;
    int p = rem % HW;
    int y = p / W, x = p % W;
    int Wp = W + 8, Hp = H + 8;
    dst[(((size_t)img * C + c) * Hp + y + 4) * Wp + x + 4] = (img ? x2 : x1)[rem];
}

// ---------------- encoder conv on padded input, 1x4 register tile, TOUT=4 cout ----------------
template <int CIN, int COUT, int K, int NSPLIT>
__global__ __launch_bounds__(256) void conv_enc_tile_k(
        const float* __restrict__ inpad, const float* __restrict__ wT,
        const float* __restrict__ bias,
        float* __restrict__ out1, float* __restrict__ out2,
        float* __restrict__ partial, int H, int W) {
    const int P = K / 2;
    const int Wp = W + 8, Hp = H + 8;
    const int NCOG = COUT / 4;
    const int CSP = CIN / NSPLIT;
    int cog = blockIdx.y % NCOG;
    int s = blockIdx.y / NCOG;
    int img = blockIdx.z;
    int tile = blockIdx.x * 256 + threadIdx.x;
    int wt = W >> 2;
    int tx = tile % wt, ty = tile / wt;
    int x0 = tx << 2;
    int og = cog * 4;
    int ci0 = s * CSP;

    float acc[4][4];
#pragma unroll
    for (int t = 0; t < 4; ++t) {
        float b = (NSPLIT == 1) ? bias[og + t] : 0.f;
#pragma unroll
        for (int p = 0; p < 4; ++p) acc[t][p] = b;
    }

    const float* ibase = inpad + ((size_t)img * CIN + ci0) * Hp * Wp;
#pragma unroll
    for (int ci = 0; ci < CSP; ++ci) {
        const float* ip = ibase + (size_t)ci * Hp * Wp;
#pragma unroll
        for (int ky = 0; ky < K; ++ky) {
            const float* rp = ip + (size_t)(ty + 4 - P + ky) * Wp + x0;  // 16B aligned
            float4 a0 = *(const float4*)(rp);
            float4 a1 = *(const float4*)(rp + 4);
            float4 a2 = *(const float4*)(rp + 8);
            float win[12] = {a0.x, a0.y, a0.z, a0.w, a1.x, a1.y, a1.z, a1.w,
                             a2.x, a2.y, a2.z, a2.w};
            const float* wrow = wT + (size_t)(((ci0 + ci) * K + ky) * K) * COUT + og;
#pragma unroll
            for (int kx = 0; kx < K; ++kx) {
                float4 wv = *(const float4*)(wrow + (size_t)kx * COUT);
#pragma unroll
                for (int p = 0; p < 4; ++p) {
                    float v = win[4 - P + kx + p];
                    acc[0][p] += v * wv.x;
                    acc[1][p] += v * wv.y;
                    acc[2][p] += v * wv.z;
                    acc[3][p] += v * wv.w;
                }
            }
        }
    }

    size_t pixbase = (size_t)ty * W + x0;
    if (NSPLIT == 1) {
        float* out = img ? out2 : out1;
#pragma unroll
        for (int t = 0; t < 4; ++t) {
            float4 r;
            r.x = leakyf(acc[t][0]); r.y = leakyf(acc[t][1]);
            r.z = leakyf(acc[t][2]); r.w = leakyf(acc[t][3]);
            *(float4*)(out + (size_t)(og + t) * H * W + pixbase) = r;
        }
    } else {
        float* pp = partial + (((size_t)s * 2 + img) * COUT + og) * H * W + pixbase;
#pragma unroll
        for (int t = 0; t < 4; ++t) {
            float4 r;
            r.x = acc[t][0]; r.y = acc[t][1]; r.z = acc[t][2]; r.w = acc[t][3];
            *(float4*)(pp + (size_t)t * H * W) = r;
        }
    }
}

// ---------------- reduce partials + bias + leaky (float4) ----------------
template <int NSPLIT>
__global__ __launch_bounds__(256) void reduce4_k(const float4* __restrict__ partial,
                                                 const float* __restrict__ bias,
                                                 float* __restrict__ out1,
                                                 float* __restrict__ out2,
                                                 int COUT, int HW) {
    int idx = blockIdx.x * 256 + threadIdx.x;  // exact grid: 2*COUT*HW/4
    int hq = HW >> 2;
    int cq = COUT * hq;
    int img = idx / cq;
    int rem = idx % cq;
    int co = rem / hq;
    float b = bias[co];
    float4 sum; sum.x = b; sum.y = b; sum.z = b; sum.w = b;
#pragma unroll
    for (int sp = 0; sp < NSPLIT; ++sp) {
        float4 v = partial[(size_t)(sp * 2 + img) * cq + rem];
        sum.x += v.x; sum.y += v.y; sum.z += v.z; sum.w += v.w;
    }
    float4 r;
    r.x = leakyf(sum.x); r.y = leakyf(sum.y); r.z = leakyf(sum.z); r.w = leakyf(sum.w);
    ((float4*)(img ? out2 : out1))[rem] = r;
}

// ---------------- 2x2 maxpool, writes into padded next-level buffer ----------------
__global__ void maxpool_pad_k(const float* __restrict__ in, float* __restrict__ outp,
                              int C, int H, int W) {
    int H2 = H >> 1, W2 = W >> 1;
    int idx = blockIdx.x * blockDim.x + threadIdx.x;  // exact grid: C*H2*W2
    int x = idx % W2;
    int y = (idx / W2) % H2;
    int c = idx / (W2 * H2);
    const float* p = in + ((size_t)c * H + 2 * y) * W + 2 * x;
    float v = fmaxf(fmaxf(p[0], p[1]), fmaxf(p[W], p[W + 1]));
    outp[((size_t)c * (H2 + 8) + y + 4) * (W2 + 8) + x + 4] = v;
}

// ---------------- gather Q = h1[:, pts] ----------------
__global__ void gatherQ_k(const float* __restrict__ h1, const int* __restrict__ pts,
                          float* __restrict__ Q, int C, int Wdim, int shift) {
    int idx = blockIdx.x * blockDim.x + threadIdx.x;
    if (idx >= C * 256) return;
    int l = idx & 255;
    int c = idx >> 8;
    int r = pts[2 * l] >> shift;
    int cc = pts[2 * l + 1] >> shift;
    Q[idx] = h1[(size_t)c * Wdim * Wdim + (size_t)r * Wdim + cc];
}

// ---------------- fused scores+softmax over the reference's SCRAMBLED chunks ----------------
template <int C, int BAND, int THREADS, int NM4>
__global__ __launch_bounds__(THREADS) void attn_fused_k(
        const float* __restrict__ h2, const float* __restrict__ Qg,
        float* __restrict__ S, int HW) {
    int lc = blockIdx.x;
    int t = threadIdx.x;
    int m0 = lc * BAND;

    __shared__ float Qs[C * 256];
    __shared__ float h2s[C * BAND];
    __shared__ float red[THREADS];

    for (int i = t; i < C * 256; i += THREADS) Qs[i] = Qg[i];
    for (int i = t; i < C * BAND; i += THREADS) {
        int c = i / BAND, j = i % BAND;
        h2s[i] = h2[(size_t)c * HW + m0 + j];
    }
    __syncthreads();

    const float4* Qs4 = (const float4*)Qs;
    float4 sreg[NM4];
    float mx = -3.4e38f;
#pragma unroll
    for (int i = 0; i < NM4; ++i) {
        int slot = t + i * THREADS;
        int mi = slot >> 6;
        int lq = slot & 63;
        float4 acc; acc.x = 0.f; acc.y = 0.f; acc.z = 0.f; acc.w = 0.f;
#pragma unroll
        for (int c = 0; c < C; ++c) {
            float hv = h2s[c * BAND + mi];
            float4 q = Qs4[c * 64 + lq];
            acc.x += hv * q.x; acc.y += hv * q.y;
            acc.z += hv * q.z; acc.w += hv * q.w;
        }
        sreg[i] = acc;
        mx = fmaxf(mx, fmaxf(fmaxf(acc.x, acc.y), fmaxf(acc.z, acc.w)));
    }

    red[t] = mx;
    __syncthreads();
    for (int o = THREADS >> 1; o > 0; o >>= 1) {
        if (t < o) red[t] = fmaxf(red[t], red[t + o]);
        __syncthreads();
    }
    float M = red[0];
    __syncthreads();

    float s = 0.f;
#pragma unroll
    for (int i = 0; i < NM4; ++i) {
        float4 e;
        e.x = __expf(sreg[i].x - M);
        e.y = __expf(sreg[i].y - M);
        e.z = __expf(sreg[i].z - M);
        e.w = __expf(sreg[i].w - M);
        sreg[i] = e;
        s += e.x + e.y + e.z + e.w;
    }
    red[t] = s;
    __syncthreads();
    for (int o = THREADS >> 1; o > 0; o >>= 1) {
        if (t < o) red[t] += red[t + o];
        __syncthreads();
    }
    float inv = 1.f / red[0];

    float4* Sp = (float4*)(S + (size_t)lc * HW);
#pragma unroll
    for (int i = 0; i < NM4; ++i) {
        float4 e = sreg[i];
        e.x *= inv; e.y *= inv; e.z *= inv; e.w *= inv;
        Sp[t + i * THREADS] = e;
    }
}

// ---------------- batch-1 convT layer0, split-K over CIN: partials ----------------
template <int NSPLIT>
__global__ __launch_bounds__(256) void convT_b1_split_k(
        const float* __restrict__ in, const float* __restrict__ w,
        float* __restrict__ partial) {
    const int CIN = 64, COUT = 32, H = 16;
    const int CSP = CIN / NSPLIT;
    int idx = blockIdx.x * 256 + threadIdx.x;   // exact grid: NSPLIT*32768
    int s = idx >> 15;
    int rem = idx & 32767;
    int x = rem & 31;
    int y = (rem >> 5) & 31;
    int o = rem >> 10;

    int kys[2], iys[2], nky, kxs[2], ixs[2], nkx;
    if (y & 1) {
        nky = 0;
        int iy0 = (y + 1) >> 1;
        if (iy0 < H) { kys[nky] = 0; iys[nky] = iy0; ++nky; }
        kys[nky] = 2; iys[nky] = (y - 1) >> 1; ++nky;
    } else { kys[0] = 1; iys[0] = y >> 1; nky = 1; }
    if (x & 1) {
        nkx = 0;
        int ix0 = (x + 1) >> 1;
        if (ix0 < H) { kxs[nkx] = 0; ixs[nkx] = ix0; ++nkx; }
        kxs[nkx] = 2; ixs[nkx] = (x - 1) >> 1; ++nkx;
    } else { kxs[0] = 1; ixs[0] = x >> 1; nkx = 1; }

    const int Wp = 24;
    float acc = 0.f;
    int ci0 = s * CSP;
#pragma unroll
    for (int c = 0; c < CSP; ++c) {
        int ci = ci0 + c;
        const float* ip = in + (size_t)ci * Wp * Wp;
        const float* wp = w + ((size_t)ci * COUT + o) * 9;
        for (int a = 0; a < nky; ++a)
            for (int b = 0; b < nkx; ++b)
                acc += ip[(size_t)(iys[a] + 4) * Wp + ixs[b] + 4] * wp[kys[a] * 3 + kxs[b]];
    }
    partial[idx] = acc;
}

// ---------------- reduce b1 partials + bias ----------------
template <int NSPLIT>
__global__ __launch_bounds__(256) void reduce_b1_k(
        const float* __restrict__ partial, const float* __restrict__ bias,
        float* __restrict__ out) {
    int idx = blockIdx.x * 256 + threadIdx.x;   // exact grid: 32768
    float sum = bias[idx >> 10];
#pragma unroll
    for (int s = 0; s < NSPLIT; ++s) sum += partial[(size_t)s * 32768 + idx];
    out[idx] = sum;
}

// ---------------- broadcast (1,C,H,W)*(256,1,H,W) + leaky ----------------
__global__ void bcast_mul_leaky_k(const float* __restrict__ t, const float* __restrict__ attn,
                                  float* __restrict__ out, int C, int HW) {
    size_t idx = (size_t)blockIdx.x * blockDim.x + threadIdx.x;
    size_t total = (size_t)256 * C * HW;
    if (idx >= total) return;
    int p = (int)(idx % HW);
    int c = (int)((idx / HW) % C);
    int n = (int)(idx / ((size_t)HW * C));
    out[idx] = leakyf(t[(size_t)c * HW + p] * attn[(size_t)n * HW + p]);
}

// ---------------- vector-weight parity-quad convT: 1 input pixel x 4 cout (per-slice dispatch) ----------------
template <int CIN, int COFULL, bool LEAKY>
__global__ __launch_bounds__(256) void convT_quadV_k(
        const float* __restrict__ in, const float* __restrict__ wtd,
        const float* __restrict__ bias, const float* __restrict__ attn,
        float* __restrict__ out, int H, int W) {
    int idx = blockIdx.x * 256 + threadIdx.x;   // exact grid
    int ix = idx % W;
    int iy = (idx / W) % H;
    int n = idx / (W * H);
    int H2 = H << 1, W2 = W << 1;
    bool okx = (ix + 1 < W), oky = (iy + 1 < H);

    float accEE[4] = {0.f, 0.f, 0.f, 0.f};
    float accEO[4] = {0.f, 0.f, 0.f, 0.f};
    float accOE[4] = {0.f, 0.f, 0.f, 0.f};
    float accOO[4] = {0.f, 0.f, 0.f, 0.f};

    const float* p = in + ((size_t)n * CIN * H + iy) * W + ix;
#pragma unroll 1
    for (int ci = 0; ci < CIN; ++ci) {
        float v00 = p[0];
        float v01 = okx ? p[1] : 0.f;
        float v10 = oky ? p[W] : 0.f;
        float v11 = (okx && oky) ? p[W + 1] : 0.f;
        const float* wr = wtd + (size_t)ci * 9 * COFULL;
        float4 w0 = *(const float4*)(wr + 0 * COFULL);
        float4 w1 = *(const float4*)(wr + 1 * COFULL);
        float4 w2 = *(const float4*)(wr + 2 * COFULL);
        float4 w3 = *(const float4*)(wr + 3 * COFULL);
        float4 w4 = *(const float4*)(wr + 4 * COFULL);
        float4 w5 = *(const float4*)(wr + 5 * COFULL);
        float4 w6 = *(const float4*)(wr + 6 * COFULL);
        float4 w7 = *(const float4*)(wr + 7 * COFULL);
        float4 w8 = *(const float4*)(wr + 8 * COFULL);
        accEE[0] += w4.x * v00; accEE[1] += w4.y * v00;
        accEE[2] += w4.z * v00; accEE[3] += w4.w * v00;
        accEO[0] += w3.x * v01 + w5.x * v00; accEO[1] += w3.y * v01 + w5.y * v00;
        accEO[2] += w3.z * v01 + w5.z * v00; accEO[3] += w3.w * v01 + w5.w * v00;
        accOE[0] += w1.x * v10 + w7.x * v00; accOE[1] += w1.y * v10 + w7.y * v00;
        accOE[2] += w1.z * v10 + w7.z * v00; accOE[3] += w1.w * v10 + w7.w * v00;
        accOO[0] += w0.x * v11 + w2.x * v10 + w6.x * v01 + w8.x * v00;
        accOO[1] += w0.y * v11 + w2.y * v10 + w6.y * v01 + w8.y * v00;
        accOO[2] += w0.z * v11 + w2.z * v10 + w6.z * v01 + w8.z * v00;
        accOO[3] += w0.w * v11 + w2.w * v10 + w6.w * v01 + w8.w * v00;
        p += H * W;
    }

    size_t abase = ((size_t)n * H2 + 2 * iy) * W2 + 2 * ix;
    float2 aT = *(const float2*)(attn + abase);
    float2 aB = *(const float2*)(attn + abase + W2);

#pragma unroll
    for (int c = 0; c < 4; ++c) {
        float b = bias[c];
        float rEE = (accEE[c] + b) * aT.x;
        float rEO = (accEO[c] + b) * aT.y;
        float rOE = (accOE[c] + b) * aB.x;
        float rOO = (accOO[c] + b) * aB.y;
        if (LEAKY) {
            rEE = leakyf(rEE); rEO = leakyf(rEO);
            rOE = leakyf(rOE); rOO = leakyf(rOO);
        }
        size_t ob = (((size_t)n * COFULL + c) * H2 + 2 * iy) * W2 + 2 * ix;
        float2 top; top.x = rEE; top.y = rEO;
        float2 bot; bot.x = rOE; bot.y = rOO;
        *(float2*)(out + ob) = top;
        *(float2*)(out + ob + W2) = bot;
    }
}

// ---------------- vector-weight parity-quad convT: 2 input pixels x 4 cout (per-slice) ----------------
template <int CIN, int COFULL, bool LEAKY>
__global__ __launch_bounds__(256) void convT_quadV2_k(
        const float* __restrict__ in, const float* __restrict__ wtd,
        const float* __restrict__ bias, const float* __restrict__ attn,
        float* __restrict__ out, int H, int W) {
    int WT = W >> 1;
    int idx = blockIdx.x * 256 + threadIdx.x;   // exact grid: N*H*WT/256
    int tx = idx % WT;
    int iy = (idx / WT) % H;
    int n = idx / (WT * H);
    int ix0 = tx << 1;
    int H2 = H << 1, W2 = W << 1;
    bool okx = (tx + 1 < WT);     // p[2] valid
    bool oky = (iy + 1 < H);

    float accT[4][4], accB[4][4];
#pragma unroll
    for (int c = 0; c < 4; ++c)
#pragma unroll
        for (int q = 0; q < 4; ++q) { accT[c][q] = 0.f; accB[c][q] = 0.f; }

    const float* p = in + ((size_t)n * CIN * H + iy) * W + ix0;
#pragma unroll 1
    for (int ci = 0; ci < CIN; ++ci) {
        float2 a01 = *(const float2*)p;
        float a2 = okx ? p[2] : 0.f;
        float av[3] = {a01.x, a01.y, a2};
        float bv[3];
        if (oky) {
            float2 b01 = *(const float2*)(p + W);
            bv[0] = b01.x; bv[1] = b01.y;
            bv[2] = okx ? p[W + 2] : 0.f;
        } else {
            bv[0] = 0.f; bv[1] = 0.f; bv[2] = 0.f;
        }
        const float* wr = wtd + (size_t)ci * 9 * COFULL;
        float4 w0 = *(const float4*)(wr + 0 * COFULL);
        float4 w1 = *(const float4*)(wr + 1 * COFULL);
        float4 w2 = *(const float4*)(wr + 2 * COFULL);
        float4 w3 = *(const float4*)(wr + 3 * COFULL);
        float4 w4 = *(const float4*)(wr + 4 * COFULL);
        float4 w5 = *(const float4*)(wr + 5 * COFULL);
        float4 w6 = *(const float4*)(wr + 6 * COFULL);
        float4 w7 = *(const float4*)(wr + 7 * COFULL);
        float4 w8 = *(const float4*)(wr + 8 * COFULL);
        const float* w0p = (const float*)&w0;
        const float* w1p = (const float*)&w1;
        const float* w2p = (const float*)&w2;
        const float* w3p = (const float*)&w3;
        const float* w4p = (const float*)&w4;
        const float* w5p = (const float*)&w5;
        const float* w6p = (const float*)&w6;
        const float* w7p = (const float*)&w7;
        const float* w8p = (const float*)&w8;
#pragma unroll
        for (int c = 0; c < 4; ++c) {
            float c0 = w0p[c], c1 = w1p[c], c2 = w2p[c], c3 = w3p[c], c4 = w4p[c],
                  c5 = w5p[c], c6 = w6p[c], c7 = w7p[c], c8 = w8p[c];
#pragma unroll
            for (int q = 0; q < 2; ++q) {
                accT[c][2 * q]     += c4 * av[q];
                accT[c][2 * q + 1] += c3 * av[q + 1] + c5 * av[q];
                accB[c][2 * q]     += c1 * bv[q] + c7 * av[q];
                accB[c][2 * q + 1] += c0 * bv[q + 1] + c2 * bv[q] + c6 * av[q + 1] + c8 * av[q];
            }
        }
        p += H * W;
    }

    size_t abase = ((size_t)n * H2 + 2 * iy) * W2 + (ix0 << 1);   // 16B aligned
    float4 aT = *(const float4*)(attn + abase);
    float4 aB = *(const float4*)(attn + abase + W2);
    const float* aTp = (const float*)&aT;
    const float* aBp = (const float*)&aB;

#pragma unroll
    for (int c = 0; c < 4; ++c) {
        float b = bias[c];
        float4 top, bot;
        float* tp = (float*)&top;
        float* bp = (float*)&bot;
#pragma unroll
        for (int q = 0; q < 4; ++q) {
            float vt = (accT[c][q] + b) * aTp[q];
            float vb = (accB[c][q] + b) * aBp[q];
            if (LEAKY) { vt = leakyf(vt); vb = leakyf(vb); }
            tp[q] = vt; bp[q] = vb;
        }
        size_t ob = (((size_t)n * COFULL + c) * H2 + 2 * iy) * W2 + (ix0 << 1);
        *(float4*)(out + ob) = top;
        *(float4*)(out + ob + W2) = bot;
    }
}

// ---------------- decoder layer 3 (COUT=1): 8-wide quads, 4x float4 loads/ci, fused valid ----------------
// One thread = input pixels (iy, 8tx..8tx+7) => output 2x16 strip at (2iy, 16tx).
__global__ __launch_bounds__(256) void convT_L3_k(
        const float* __restrict__ in, const float* __restrict__ w,
        const float* __restrict__ bias, const float* __restrict__ attn,
        float* __restrict__ out, int* __restrict__ validFlag) {
    const int H = 128, W = 128, CIN = 8;
    int idx = blockIdx.x * 256 + threadIdx.x;   // exact grid: 256*128*16 threads
    int tx = idx & 15;
    int iy = (idx >> 4) & 127;
    int n = idx >> 11;                           // 2048 threads per n (8 blocks)
    int ix0 = tx << 3;
    bool okx = (tx < 15);
    bool oky = (iy + 1 < H);

    float acc[8][4];
#pragma unroll
    for (int q = 0; q < 8; ++q) {
        acc[q][0] = 0.f; acc[q][1] = 0.f; acc[q][2] = 0.f; acc[q][3] = 0.f;
    }

    const float* p = in + ((size_t)n * CIN * H + iy) * W + ix0;
#pragma unroll 1
    for (int ci = 0; ci < CIN; ++ci) {
        float4 a0 = *(const float4*)p;
        float4 a1 = *(const float4*)(p + 4);
        float a8 = okx ? p[8] : 0.f;
        float av[9] = {a0.x, a0.y, a0.z, a0.w, a1.x, a1.y, a1.z, a1.w, a8};
        float bv[9];
        if (oky) {
            float4 b0 = *(const float4*)(p + W);
            float4 b1 = *(const float4*)(p + W + 4);
            bv[0] = b0.x; bv[1] = b0.y; bv[2] = b0.z; bv[3] = b0.w;
            bv[4] = b1.x; bv[5] = b1.y; bv[6] = b1.z; bv[7] = b1.w;
            bv[8] = okx ? p[W + 8] : 0.f;
        } else {
#pragma unroll
            for (int j = 0; j < 9; ++j) bv[j] = 0.f;
        }
        const float* qw = w + ci * 9;   // wave-uniform -> SGPR
        float w0 = qw[0], w1 = qw[1], w2 = qw[2], w3 = qw[3], w4 = qw[4],
              w5 = qw[5], w6 = qw[6], w7 = qw[7], w8 = qw[8];
#pragma unroll
        for (int q = 0; q < 8; ++q) {
            acc[q][0] += w4 * av[q];
            acc[q][1] += w3 * av[q + 1] + w5 * av[q];
            acc[q][2] += w1 * bv[q] + w7 * av[q];
            acc[q][3] += w0 * bv[q + 1] + w2 * bv[q] + w6 * av[q + 1] + w8 * av[q];
        }
        p += H * W;
    }

    const int W2 = 256;
    size_t abase = ((size_t)n * 256 + 2 * iy) * W2 + (ix0 << 1);   // 64B aligned
    float bs = bias[0];
    float vmax = -3.4e38f;
#pragma unroll
    for (int g = 0; g < 4; ++g) {
        float4 aT = *(const float4*)(attn + abase + 4 * g);
        float4 aB = *(const float4*)(attn + abase + W2 + 4 * g);
        float4 top, bot;
        top.x = (acc[2 * g][0] + bs) * aT.x;
        top.y = (acc[2 * g][1] + bs) * aT.y;
        top.z = (acc[2 * g + 1][0] + bs) * aT.z;
        top.w = (acc[2 * g + 1][1] + bs) * aT.w;
        bot.x = (acc[2 * g][2] + bs) * aB.x;
        bot.y = (acc[2 * g][3] + bs) * aB.y;
        bot.z = (acc[2 * g + 1][2] + bs) * aB.z;
        bot.w = (acc[2 * g + 1][3] + bs) * aB.w;
        *(float4*)(out + abase + 4 * g) = top;
        *(float4*)(out + abase + W2 + 4 * g) = bot;
        vmax = fmaxf(vmax,
            fmaxf(fmaxf(fmaxf(top.x, top.y), fmaxf(top.z, top.w)),
                  fmaxf(fmaxf(bot.x, bot.y), fmaxf(bot.z, bot.w))));
    }

    __shared__ float smax[256];
    int t = threadIdx.x;
    smax[t] = vmax;
    __syncthreads();
    for (int o = 128; o > 0; o >>= 1) {
        if (t < o) smax[t] = fmaxf(smax[t], smax[t + o]);
        __syncthreads();
    }
    if (t == 0 && smax[0] > 1.f) atomicOr(&validFlag[n], 1);
}

// ---------------- decode valid flags ----------------
__global__ void valid_decode_k(const int* __restrict__ flags, float* __restrict__ vout) {
    int l = threadIdx.x;
    vout[l] = flags[l] ? 1.f : 0.f;
}

extern "C" void kernel_launch(void* const* d_in, const int* in_sizes, int n_in,
                              void* d_out, int out_size, void* d_ws, size_t ws_size,
                              hipStream_t stream) {
    const float* x1 = (const float*)d_in[0];
    const float* x2 = (const float*)d_in[1];
    const int* pts = (const int*)d_in[2];
    const float* ew[4] = {(const float*)d_in[3], (const float*)d_in[5], (const float*)d_in[7], (const float*)d_in[9]};
    const float* eb[4] = {(const float*)d_in[4], (const float*)d_in[6], (const float*)d_in[8], (const float*)d_in[10]};
    const float* dw[4] = {(const float*)d_in[11], (const float*)d_in[13], (const float*)d_in[15], (const float*)d_in[17]};
    const float* db[4] = {(const float*)d_in[12], (const float*)d_in[14], (const float*)d_in[16], (const float*)d_in[18]};

    float* ws = (float*)d_ws;
    float* h1a = ws;                    // 524288
    float* h2a = h1a + 524288;          // 524288
    float* Q   = h2a + 524288;          // 16384
    float* t0  = Q + 16384;             // 32768
    float* attn3 = t0 + 32768;          // 262144   (32x32 * 256)
    float* attn2 = attn3 + 262144;      // 1048576  (64x64 * 256)
    float* attn1 = attn2 + 1048576;     // 4194304  (128x128 * 256)
    float* attn0 = attn1 + 4194304;     // 16777216 (256x256 * 256)
    float* bufD1 = attn0 + 16777216;    // 33554432
    float* wT0 = bufD1 + 33554432;      // 216
    float* wT1 = wT0 + 216;             // 3200
    float* wT2 = wT1 + 3200;            // 25088
    float* wT3 = wT2 + 25088;           // 165888
    int* validFlag = (int*)(wT3 + 165888);  // 256 ints
    float* wtd1 = (float*)(validFlag + 256);  // 32*16*9 = 4608
    float* wtd2 = wtd1 + 4608;                // 16*8*9 = 1152
    float* h2a0 = wtd2 + 1152;                // 524288 (dedicated lv0 h2 for deferred attn)
    float* Q0   = h2a0 + 524288;              // 2048   (8*256)
    // pad buffers alias the FRONT of bufD1 (dead until decoder)
    float* pad0 = bufD1;                // 2*3*264*264  = 418176
    float* pad1 = pad0 + 418176;        // 2*8*136*136  = 295936
    float* pad2 = pad1 + 295936;        // 2*16*72*72   = 165888
    float* pad3 = pad2 + 165888;        // 2*32*40*40   = 102400
    float* pad4 = pad3 + 102400;        // 2*64*24*24   = 73728   (total 1056128)
    // partial buffer aliases bufD1 AFTER the pads (also dead until decoder;
    // b1 split partials also live here, consumed by reduce_b1 before bcast_mul overwrites bufD1)
    float* partialBuf = bufD1 + 1056768;   // 16B-aligned; ends well inside bufD1
    float* attnArr[4] = {attn0, attn1, attn2, attn3};

    float* conf = (float*)d_out;            // 16777216
    float* validOut = conf + 16777216;      // 256

    // zero pad borders (whole pad region) + valid flags each call
    hipMemsetAsync(pad0, 0, (size_t)1056128 * 4, stream);
    hipMemsetAsync(validFlag, 0, 256 * 4, stream);

    // weight pre-transpose (tiny)
    wtrans_k<<<(216 + 255) / 256, 256, 0, stream>>>(ew[0], wT0, 3, 8, 9);
    wtrans_k<<<(3200 + 255) / 256, 256, 0, stream>>>(ew[1], wT1, 8, 16, 25);
    wtrans_k<<<(25088 + 255) / 256, 256, 0, stream>>>(ew[2], wT2, 16, 32, 49);
    wtrans_k<<<(165888 + 255) / 256, 256, 0, stream>>>(ew[3], wT3, 32, 64, 81);
    wtransD_k<<<(4608 + 255) / 256, 256, 0, stream>>>(dw[1], wtd1, 32, 16);
    wtransD_k<<<(1152 + 255) / 256, 256, 0, stream>>>(dw[2], wtd2, 16, 8);

    // stage level-0 inputs into padded layout
    pad_in_k<<<(2 * 3 * 65536) / 256, 256, 0, stream>>>(x1, x2, pad0, 3, 256, 256);

    const int Hs[4] = {256, 128, 64, 32};
    const int Couts[4] = {8, 16, 32, 64};
    float* padIn[4] = {pad0, pad1, pad2, pad3};
    float* padOut[4] = {pad1, pad2, pad3, pad4};
    const int padOutImgStride[4] = {8 * 136 * 136, 16 * 72 * 72, 32 * 40 * 40, 64 * 24 * 24};

    for (int lv = 0; lv < 4; ++lv) {
        int Hc = Hs[lv], HW = Hc * Hc;
        float* h2dst = (lv == 0) ? h2a0 : h2a;   // lv0 h2 kept alive for deferred attn
        if (lv == 0) {
            dim3 grid(HW / 4 / 256, 2 * 1, 2);   // (64, 2, 2)
            conv_enc_tile_k<3, 8, 3, 1><<<grid, 256, 0, stream>>>(
                padIn[0], wT0, eb[0], h1a, h2dst, partialBuf, Hc, Hc);
        } else if (lv == 1) {
            dim3 grid(HW / 4 / 256, 4 * 8, 2);   // (16, 32, 2) = 1024 blocks
            conv_enc_tile_k<8, 16, 5, 8><<<grid, 256, 0, stream>>>(
                padIn[1], wT1, eb[1], h1a, h2a, partialBuf, Hc, Hc);
            reduce4_k<8><<<(2 * 16 * HW / 4) / 256, 256, 0, stream>>>(
                (const float4*)partialBuf, eb[1], h1a, h2a, 16, HW);
        } else if (lv == 2) {
            dim3 grid(HW / 4 / 256, 8 * 16, 2);  // (4, 128, 2) = 1024 blocks
            conv_enc_tile_k<16, 32, 7, 16><<<grid, 256, 0, stream>>>(
                padIn[2], wT2, eb[2], h1a, h2a, partialBuf, Hc, Hc);
            reduce4_k<16><<<(2 * 32 * HW / 4) / 256, 256, 0, stream>>>(
                (const float4*)partialBuf, eb[2], h1a, h2a, 32, HW);
        } else {
            dim3 grid(HW / 4 / 256, 16 * 32, 2); // (1, 512, 2) = 1024 blocks
            conv_enc_tile_k<32, 64, 9, 32><<<grid, 256, 0, stream>>>(
                padIn[3], wT3, eb[3], h1a, h2a, partialBuf, Hc, Hc);
            reduce4_k<32><<<(2 * 64 * HW / 4) / 256, 256, 0, stream>>>(
                (const float4*)partialBuf, eb[3], h1a, h2a, 64, HW);
        }
        gatherQ_k<<<(Couts[lv] * 256 + 255) / 256, 256, 0, stream>>>(
            h1a, pts, (lv == 0) ? Q0 : Q, Couts[lv], Hc, lv);
        // attention: lv0 DEFERRED to just before L3
        if (lv == 1)
            attn_fused_k<16, 64, 1024, 4><<<256, 1024, 0, stream>>>(h2a, Q, attnArr[1], HW);
        else if (lv == 2)
            attn_fused_k<32, 16, 1024, 1><<<256, 1024, 0, stream>>>(h2a, Q, attnArr[2], HW);
        else if (lv == 3)
            attn_fused_k<64, 4, 256, 1><<<256, 256, 0, stream>>>(h2a, Q, attnArr[3], HW);
        int npool = Couts[lv] * (HW / 4);
        maxpool_pad_k<<<npool / 256, 256, 0, stream>>>(h1a, padOut[lv], Couts[lv], Hc, Hc);
        maxpool_pad_k<<<npool / 256, 256, 0, stream>>>(h2dst, padOut[lv] + padOutImgStride[lv],
                                                       Couts[lv], Hc, Hc);
    }
    // pad4 img1 section now holds padded encoder output of image 2 (64,16,16)

    // decoder layer 0: split-K convT at batch 1 (16 splits -> 2048 blocks), then reduce+bias
    convT_b1_split_k<16><<<(16 * 32768) / 256, 256, 0, stream>>>(
        pad4 + padOutImgStride[3], dw[0], partialBuf);
    reduce_b1_k<16><<<32768 / 256, 256, 0, stream>>>(partialBuf, db[0], t0);
    // broadcast*attn3 + leaky -> bufD1 (256,32,32,32)
    {
        size_t tot = (size_t)256 * 32 * 1024;
        bcast_mul_leaky_k<<<(unsigned)((tot + 255) / 256), 256, 0, stream>>>(t0, attn3, bufD1, 32, 1024);
    }
    // layer 1: (256,32,32,32) -> (256,16,64,64) * attn2, leaky -> conf (staging)
    {
        int tot = 256 * 32 * 32;   // 1024 blocks per dispatch
        for (int s = 0; s < 4; ++s) {
            convT_quadV_k<32, 16, true><<<tot / 256, 256, 0, stream>>>(
                bufD1, wtd1 + s * 4, db[1] + s * 4, attn2,
                conf + (size_t)(s * 4) * 64 * 64, 32, 32);
        }
    }
    // layer 2: (256,16,64,64) -> (256,8,128,128) * attn1, leaky -> bufD1
    {
        int tot = 256 * 64 * 32;   // 2048 blocks per dispatch
        for (int s = 0; s < 2; ++s) {
            convT_quadV2_k<16, 8, true><<<tot / 256, 256, 0, stream>>>(
                conf, wtd2 + s * 4, db[2] + s * 4, attn1,
                bufD1 + (size_t)(s * 4) * 128 * 128, 64, 64);
        }
    }
    // DEFERRED level-0 attention: attn0 computed just before its consumer
    attn_fused_k<8, 256, 1024, 16><<<256, 1024, 0, stream>>>(h2a0, Q0, attn0, 65536);
    // layer 3: (256,8,128,128) -> (256,1,256,256) * attn0, no leaky -> conf, fused valid (8-wide)
    {
        int tot = 256 * 128 * 16;   // 2048 blocks
        convT_L3_k<<<tot / 256, 256, 0, stream>>>(
            bufD1, dw[3], db[3], attn0, conf, validFlag);
    }
    valid_decode_k<<<1, 256, 0, stream>>>(validFlag, validOut);
}

// Round 22
// 410.953 us; speedup vs baseline: 1.0328x; 1.0328x over previous
//
#include <hip/hip_runtime.h>
#include <cstdint>
#include <cstddef>

#define NEG_SLOPE 0.01f

__device__ __forceinline__ float leakyf(float v) { return v > 0.f ? v : NEG_SLOPE * v; }

// ---------------- weight transpose: w[co][ci][k][k] -> wT[ci][k][k][co] ----------------
__global__ void wtrans_k(const float* __restrict__ w, float* __restrict__ wT,
                         int CIN, int COUT, int KK) {
    int idx = blockIdx.x * blockDim.x + threadIdx.x;
    int total = COUT * CIN * KK;
    if (idx >= total) return;
    int co = idx / (CIN * KK);
    int rem = idx % (CIN * KK);
    wT[(size_t)rem * COUT + co] = w[idx];
}

// ---------------- decoder weight transpose: w[ci][co][9] -> wtd[ci][9][co] ----------------
__global__ void wtransD_k(const float* __restrict__ w, float* __restrict__ wtd,
                          int CIN, int COUT) {
    int idx = blockIdx.x * blockDim.x + threadIdx.x;
    int total = CIN * COUT * 9;
    if (idx >= total) return;
    int ci = idx / (COUT * 9);
    int r = idx % (COUT * 9);
    int co = r / 9;
    int t = r % 9;
    wtd[((size_t)ci * 9 + t) * COUT + co] = w[idx];
}

// ---------------- pad input images into zero-bordered buffer [2][3][H+8][W+8] ----------------
__global__ void pad_in_k(const float* __restrict__ x1, const float* __restrict__ x2,
                         float* __restrict__ dst, int C, int H, int W) {
    int idx = blockIdx.x * blockDim.x + threadIdx.x;  // exact grid: 2*C*H*W
    int HW = H * W;
    int img = idx / (C * HW);
    int rem = idx % (C * HW);
    int c = rem / HW;
    int p = rem % HW;
    int y = p / W, x = p % W;
    int Wp = W + 8, Hp = H + 8;
    dst[(((size_t)img * C + c) * Hp + y + 4) * Wp + x + 4] = (img ? x2 : x1)[rem];
}

// ---------------- encoder conv on padded input, 1x4 register tile, TOUT=4 cout ----------------
template <int CIN, int COUT, int K, int NSPLIT>
__global__ __launch_bounds__(256) void conv_enc_tile_k(
        const float* __restrict__ inpad, const float* __restrict__ wT,
        const float* __restrict__ bias,
        float* __restrict__ out1, float* __restrict__ out2,
        float* __restrict__ partial, int H, int W) {
    const int P = K / 2;
    const int Wp = W + 8, Hp = H + 8;
    const int NCOG = COUT / 4;
    const int CSP = CIN / NSPLIT;
    int cog = blockIdx.y % NCOG;
    int s = blockIdx.y / NCOG;
    int img = blockIdx.z;
    int tile = blockIdx.x * 256 + threadIdx.x;
    int wt = W >> 2;
    int tx = tile % wt, ty = tile / wt;
    int x0 = tx << 2;
    int og = cog * 4;
    int ci0 = s * CSP;

    float acc[4][4];
#pragma unroll
    for (int t = 0; t < 4; ++t) {
        float b = (NSPLIT == 1) ? bias[og + t] : 0.f;
#pragma unroll
        for (int p = 0; p < 4; ++p) acc[t][p] = b;
    }

    const float* ibase = inpad + ((size_t)img * CIN + ci0) * Hp * Wp;
#pragma unroll
    for (int ci = 0; ci < CSP; ++ci) {
        const float* ip = ibase + (size_t)ci * Hp * Wp;
#pragma unroll
        for (int ky = 0; ky < K; ++ky) {
            const float* rp = ip + (size_t)(ty + 4 - P + ky) * Wp + x0;  // 16B aligned
            float4 a0 = *(const float4*)(rp);
            float4 a1 = *(const float4*)(rp + 4);
            float4 a2 = *(const float4*)(rp + 8);
            float win[12] = {a0.x, a0.y, a0.z, a0.w, a1.x, a1.y, a1.z, a1.w,
                             a2.x, a2.y, a2.z, a2.w};
            const float* wrow = wT + (size_t)(((ci0 + ci) * K + ky) * K) * COUT + og;
#pragma unroll
            for (int kx = 0; kx < K; ++kx) {
                float4 wv = *(const float4*)(wrow + (size_t)kx * COUT);
#pragma unroll
                for (int p = 0; p < 4; ++p) {
                    float v = win[4 - P + kx + p];
                    acc[0][p] += v * wv.x;
                    acc[1][p] += v * wv.y;
                    acc[2][p] += v * wv.z;
                    acc[3][p] += v * wv.w;
                }
            }
        }
    }

    size_t pixbase = (size_t)ty * W + x0;
    if (NSPLIT == 1) {
        float* out = img ? out2 : out1;
#pragma unroll
        for (int t = 0; t < 4; ++t) {
            float4 r;
            r.x = leakyf(acc[t][0]); r.y = leakyf(acc[t][1]);
            r.z = leakyf(acc[t][2]); r.w = leakyf(acc[t][3]);
            *(float4*)(out + (size_t)(og + t) * H * W + pixbase) = r;
        }
    } else {
        float* pp = partial + (((size_t)s * 2 + img) * COUT + og) * H * W + pixbase;
#pragma unroll
        for (int t = 0; t < 4; ++t) {
            float4 r;
            r.x = acc[t][0]; r.y = acc[t][1]; r.z = acc[t][2]; r.w = acc[t][3];
            *(float4*)(pp + (size_t)t * H * W) = r;
        }
    }
}

// ---------------- reduce partials + bias + leaky (float4) ----------------
template <int NSPLIT>
__global__ __launch_bounds__(256) void reduce4_k(const float4* __restrict__ partial,
                                                 const float* __restrict__ bias,
                                                 float* __restrict__ out1,
                                                 float* __restrict__ out2,
                                                 int COUT, int HW) {
    int idx = blockIdx.x * 256 + threadIdx.x;  // exact grid: 2*COUT*HW/4
    int hq = HW >> 2;
    int cq = COUT * hq;
    int img = idx / cq;
    int rem = idx % cq;
    int co = rem / hq;
    float b = bias[co];
    float4 sum; sum.x = b; sum.y = b; sum.z = b; sum.w = b;
#pragma unroll
    for (int sp = 0; sp < NSPLIT; ++sp) {
        float4 v = partial[(size_t)(sp * 2 + img) * cq + rem];
        sum.x += v.x; sum.y += v.y; sum.z += v.z; sum.w += v.w;
    }
    float4 r;
    r.x = leakyf(sum.x); r.y = leakyf(sum.y); r.z = leakyf(sum.z); r.w = leakyf(sum.w);
    ((float4*)(img ? out2 : out1))[rem] = r;
}

// ---------------- 2x2 maxpool, writes into padded next-level buffer ----------------
__global__ void maxpool_pad_k(const float* __restrict__ in, float* __restrict__ outp,
                              int C, int H, int W) {
    int H2 = H >> 1, W2 = W >> 1;
    int idx = blockIdx.x * blockDim.x + threadIdx.x;  // exact grid: C*H2*W2
    int x = idx % W2;
    int y = (idx / W2) % H2;
    int c = idx / (W2 * H2);
    const float* p = in + ((size_t)c * H + 2 * y) * W + 2 * x;
    float v = fmaxf(fmaxf(p[0], p[1]), fmaxf(p[W], p[W + 1]));
    outp[((size_t)c * (H2 + 8) + y + 4) * (W2 + 8) + x + 4] = v;
}

// ---------------- gather Q = h1[:, pts] ----------------
__global__ void gatherQ_k(const float* __restrict__ h1, const int* __restrict__ pts,
                          float* __restrict__ Q, int C, int Wdim, int shift) {
    int idx = blockIdx.x * blockDim.x + threadIdx.x;
    if (idx >= C * 256) return;
    int l = idx & 255;
    int c = idx >> 8;
    int r = pts[2 * l] >> shift;
    int cc = pts[2 * l + 1] >> shift;
    Q[idx] = h1[(size_t)c * Wdim * Wdim + (size_t)r * Wdim + cc];
}

// ---------------- fused scores+softmax over the reference's SCRAMBLED chunks ----------------
template <int C, int BAND, int THREADS, int NM4>
__global__ __launch_bounds__(THREADS) void attn_fused_k(
        const float* __restrict__ h2, const float* __restrict__ Qg,
        float* __restrict__ S, int HW) {
    int lc = blockIdx.x;
    int t = threadIdx.x;
    int m0 = lc * BAND;

    __shared__ float Qs[C * 256];
    __shared__ float h2s[C * BAND];
    __shared__ float red[THREADS];

    for (int i = t; i < C * 256; i += THREADS) Qs[i] = Qg[i];
    for (int i = t; i < C * BAND; i += THREADS) {
        int c = i / BAND, j = i % BAND;
        h2s[i] = h2[(size_t)c * HW + m0 + j];
    }
    __syncthreads();

    const float4* Qs4 = (const float4*)Qs;
    float4 sreg[NM4];
    float mx = -3.4e38f;
#pragma unroll
    for (int i = 0; i < NM4; ++i) {
        int slot = t + i * THREADS;
        int mi = slot >> 6;
        int lq = slot & 63;
        float4 acc; acc.x = 0.f; acc.y = 0.f; acc.z = 0.f; acc.w = 0.f;
#pragma unroll
        for (int c = 0; c < C; ++c) {
            float hv = h2s[c * BAND + mi];
            float4 q = Qs4[c * 64 + lq];
            acc.x += hv * q.x; acc.y += hv * q.y;
            acc.z += hv * q.z; acc.w += hv * q.w;
        }
        sreg[i] = acc;
        mx = fmaxf(mx, fmaxf(fmaxf(acc.x, acc.y), fmaxf(acc.z, acc.w)));
    }

    red[t] = mx;
    __syncthreads();
    for (int o = THREADS >> 1; o > 0; o >>= 1) {
        if (t < o) red[t] = fmaxf(red[t], red[t + o]);
        __syncthreads();
    }
    float M = red[0];
    __syncthreads();

    float s = 0.f;
#pragma unroll
    for (int i = 0; i < NM4; ++i) {
        float4 e;
        e.x = __expf(sreg[i].x - M);
        e.y = __expf(sreg[i].y - M);
        e.z = __expf(sreg[i].z - M);
        e.w = __expf(sreg[i].w - M);
        sreg[i] = e;
        s += e.x + e.y + e.z + e.w;
    }
    red[t] = s;
    __syncthreads();
    for (int o = THREADS >> 1; o > 0; o >>= 1) {
        if (t < o) red[t] += red[t + o];
        __syncthreads();
    }
    float inv = 1.f / red[0];

    float4* Sp = (float4*)(S + (size_t)lc * HW);
#pragma unroll
    for (int i = 0; i < NM4; ++i) {
        float4 e = sreg[i];
        e.x *= inv; e.y *= inv; e.z *= inv; e.w *= inv;
        Sp[t + i * THREADS] = e;
    }
}

// ---------------- batch-1 convT layer0, split-K over CIN: partials ----------------
template <int NSPLIT>
__global__ __launch_bounds__(256) void convT_b1_split_k(
        const float* __restrict__ in, const float* __restrict__ w,
        float* __restrict__ partial) {
    const int CIN = 64, COUT = 32, H = 16;
    const int CSP = CIN / NSPLIT;
    int idx = blockIdx.x * 256 + threadIdx.x;   // exact grid: NSPLIT*32768
    int s = idx >> 15;
    int rem = idx & 32767;
    int x = rem & 31;
    int y = (rem >> 5) & 31;
    int o = rem >> 10;

    int kys[2], iys[2], nky, kxs[2], ixs[2], nkx;
    if (y & 1) {
        nky = 0;
        int iy0 = (y + 1) >> 1;
        if (iy0 < H) { kys[nky] = 0; iys[nky] = iy0; ++nky; }
        kys[nky] = 2; iys[nky] = (y - 1) >> 1; ++nky;
    } else { kys[0] = 1; iys[0] = y >> 1; nky = 1; }
    if (x & 1) {
        nkx = 0;
        int ix0 = (x + 1) >> 1;
        if (ix0 < H) { kxs[nkx] = 0; ixs[nkx] = ix0; ++nkx; }
        kxs[nkx] = 2; ixs[nkx] = (x - 1) >> 1; ++nkx;
    } else { kxs[0] = 1; ixs[0] = x >> 1; nkx = 1; }

    const int Wp = 24;
    float acc = 0.f;
    int ci0 = s * CSP;
#pragma unroll
    for (int c = 0; c < CSP; ++c) {
        int ci = ci0 + c;
        const float* ip = in + (size_t)ci * Wp * Wp;
        const float* wp = w + ((size_t)ci * COUT + o) * 9;
        for (int a = 0; a < nky; ++a)
            for (int b = 0; b < nkx; ++b)
                acc += ip[(size_t)(iys[a] + 4) * Wp + ixs[b] + 4] * wp[kys[a] * 3 + kxs[b]];
    }
    partial[idx] = acc;
}

// ---------------- reduce b1 partials + bias ----------------
template <int NSPLIT>
__global__ __launch_bounds__(256) void reduce_b1_k(
        const float* __restrict__ partial, const float* __restrict__ bias,
        float* __restrict__ out) {
    int idx = blockIdx.x * 256 + threadIdx.x;   // exact grid: 32768
    float sum = bias[idx >> 10];
#pragma unroll
    for (int s = 0; s < NSPLIT; ++s) sum += partial[(size_t)s * 32768 + idx];
    out[idx] = sum;
}

// ---------------- broadcast (1,C,H,W)*(256,1,H,W) + leaky ----------------
__global__ void bcast_mul_leaky_k(const float* __restrict__ t, const float* __restrict__ attn,
                                  float* __restrict__ out, int C, int HW) {
    size_t idx = (size_t)blockIdx.x * blockDim.x + threadIdx.x;
    size_t total = (size_t)256 * C * HW;
    if (idx >= total) return;
    int p = (int)(idx % HW);
    int c = (int)((idx / HW) % C);
    int n = (int)(idx / ((size_t)HW * C));
    out[idx] = leakyf(t[(size_t)c * HW + p] * attn[(size_t)n * HW + p]);
}

// ---------------- vector-weight parity-quad convT: 1 input pixel x 4 cout (per-slice dispatch) ----------------
template <int CIN, int COFULL, bool LEAKY>
__global__ __launch_bounds__(256) void convT_quadV_k(
        const float* __restrict__ in, const float* __restrict__ wtd,
        const float* __restrict__ bias, const float* __restrict__ attn,
        float* __restrict__ out, int H, int W) {
    int idx = blockIdx.x * 256 + threadIdx.x;   // exact grid
    int ix = idx % W;
    int iy = (idx / W) % H;
    int n = idx / (W * H);
    int H2 = H << 1, W2 = W << 1;
    bool okx = (ix + 1 < W), oky = (iy + 1 < H);

    float accEE[4] = {0.f, 0.f, 0.f, 0.f};
    float accEO[4] = {0.f, 0.f, 0.f, 0.f};
    float accOE[4] = {0.f, 0.f, 0.f, 0.f};
    float accOO[4] = {0.f, 0.f, 0.f, 0.f};

    const float* p = in + ((size_t)n * CIN * H + iy) * W + ix;
#pragma unroll 1
    for (int ci = 0; ci < CIN; ++ci) {
        float v00 = p[0];
        float v01 = okx ? p[1] : 0.f;
        float v10 = oky ? p[W] : 0.f;
        float v11 = (okx && oky) ? p[W + 1] : 0.f;
        const float* wr = wtd + (size_t)ci * 9 * COFULL;
        float4 w0 = *(const float4*)(wr + 0 * COFULL);
        float4 w1 = *(const float4*)(wr + 1 * COFULL);
        float4 w2 = *(const float4*)(wr + 2 * COFULL);
        float4 w3 = *(const float4*)(wr + 3 * COFULL);
        float4 w4 = *(const float4*)(wr + 4 * COFULL);
        float4 w5 = *(const float4*)(wr + 5 * COFULL);
        float4 w6 = *(const float4*)(wr + 6 * COFULL);
        float4 w7 = *(const float4*)(wr + 7 * COFULL);
        float4 w8 = *(const float4*)(wr + 8 * COFULL);
        accEE[0] += w4.x * v00; accEE[1] += w4.y * v00;
        accEE[2] += w4.z * v00; accEE[3] += w4.w * v00;
        accEO[0] += w3.x * v01 + w5.x * v00; accEO[1] += w3.y * v01 + w5.y * v00;
        accEO[2] += w3.z * v01 + w5.z * v00; accEO[3] += w3.w * v01 + w5.w * v00;
        accOE[0] += w1.x * v10 + w7.x * v00; accOE[1] += w1.y * v10 + w7.y * v00;
        accOE[2] += w1.z * v10 + w7.z * v00; accOE[3] += w1.w * v10 + w7.w * v00;
        accOO[0] += w0.x * v11 + w2.x * v10 + w6.x * v01 + w8.x * v00;
        accOO[1] += w0.y * v11 + w2.y * v10 + w6.y * v01 + w8.y * v00;
        accOO[2] += w0.z * v11 + w2.z * v10 + w6.z * v01 + w8.z * v00;
        accOO[3] += w0.w * v11 + w2.w * v10 + w6.w * v01 + w8.w * v00;
        p += H * W;
    }

    size_t abase = ((size_t)n * H2 + 2 * iy) * W2 + 2 * ix;
    float2 aT = *(const float2*)(attn + abase);
    float2 aB = *(const float2*)(attn + abase + W2);

#pragma unroll
    for (int c = 0; c < 4; ++c) {
        float b = bias[c];
        float rEE = (accEE[c] + b) * aT.x;
        float rEO = (accEO[c] + b) * aT.y;
        float rOE = (accOE[c] + b) * aB.x;
        float rOO = (accOO[c] + b) * aB.y;
        if (LEAKY) {
            rEE = leakyf(rEE); rEO = leakyf(rEO);
            rOE = leakyf(rOE); rOO = leakyf(rOO);
        }
        size_t ob = (((size_t)n * COFULL + c) * H2 + 2 * iy) * W2 + 2 * ix;
        float2 top; top.x = rEE; top.y = rEO;
        float2 bot; bot.x = rOE; bot.y = rOO;
        *(float2*)(out + ob) = top;
        *(float2*)(out + ob + W2) = bot;
    }
}

// ---------------- vector-weight parity-quad convT: 2 input pixels x 4 cout (per-slice) ----------------
template <int CIN, int COFULL, bool LEAKY>
__global__ __launch_bounds__(256) void convT_quadV2_k(
        const float* __restrict__ in, const float* __restrict__ wtd,
        const float* __restrict__ bias, const float* __restrict__ attn,
        float* __restrict__ out, int H, int W) {
    int WT = W >> 1;
    int idx = blockIdx.x * 256 + threadIdx.x;   // exact grid: N*H*WT/256
    int tx = idx % WT;
    int iy = (idx / WT) % H;
    int n = idx / (WT * H);
    int ix0 = tx << 1;
    int H2 = H << 1, W2 = W << 1;
    bool okx = (tx + 1 < WT);     // p[2] valid
    bool oky = (iy + 1 < H);

    float accT[4][4], accB[4][4];
#pragma unroll
    for (int c = 0; c < 4; ++c)
#pragma unroll
        for (int q = 0; q < 4; ++q) { accT[c][q] = 0.f; accB[c][q] = 0.f; }

    const float* p = in + ((size_t)n * CIN * H + iy) * W + ix0;
#pragma unroll 1
    for (int ci = 0; ci < CIN; ++ci) {
        float2 a01 = *(const float2*)p;
        float a2 = okx ? p[2] : 0.f;
        float av[3] = {a01.x, a01.y, a2};
        float bv[3];
        if (oky) {
            float2 b01 = *(const float2*)(p + W);
            bv[0] = b01.x; bv[1] = b01.y;
            bv[2] = okx ? p[W + 2] : 0.f;
        } else {
            bv[0] = 0.f; bv[1] = 0.f; bv[2] = 0.f;
        }
        const float* wr = wtd + (size_t)ci * 9 * COFULL;
        float4 w0 = *(const float4*)(wr + 0 * COFULL);
        float4 w1 = *(const float4*)(wr + 1 * COFULL);
        float4 w2 = *(const float4*)(wr + 2 * COFULL);
        float4 w3 = *(const float4*)(wr + 3 * COFULL);
        float4 w4 = *(const float4*)(wr + 4 * COFULL);
        float4 w5 = *(const float4*)(wr + 5 * COFULL);
        float4 w6 = *(const float4*)(wr + 6 * COFULL);
        float4 w7 = *(const float4*)(wr + 7 * COFULL);
        float4 w8 = *(const float4*)(wr + 8 * COFULL);
        const float* w0p = (const float*)&w0;
        const float* w1p = (const float*)&w1;
        const float* w2p = (const float*)&w2;
        const float* w3p = (const float*)&w3;
        const float* w4p = (const float*)&w4;
        const float* w5p = (const float*)&w5;
        const float* w6p = (const float*)&w6;
        const float* w7p = (const float*)&w7;
        const float* w8p = (const float*)&w8;
#pragma unroll
        for (int c = 0; c < 4; ++c) {
            float c0 = w0p[c], c1 = w1p[c], c2 = w2p[c], c3 = w3p[c], c4 = w4p[c],
                  c5 = w5p[c], c6 = w6p[c], c7 = w7p[c], c8 = w8p[c];
#pragma unroll
            for (int q = 0; q < 2; ++q) {
                accT[c][2 * q]     += c4 * av[q];
                accT[c][2 * q + 1] += c3 * av[q + 1] + c5 * av[q];
                accB[c][2 * q]     += c1 * bv[q] + c7 * av[q];
                accB[c][2 * q + 1] += c0 * bv[q + 1] + c2 * bv[q] + c6 * av[q + 1] + c8 * av[q];
            }
        }
        p += H * W;
    }

    size_t abase = ((size_t)n * H2 + 2 * iy) * W2 + (ix0 << 1);   // 16B aligned
    float4 aT = *(const float4*)(attn + abase);
    float4 aB = *(const float4*)(attn + abase + W2);
    const float* aTp = (const float*)&aT;
    const float* aBp = (const float*)&aB;

#pragma unroll
    for (int c = 0; c < 4; ++c) {
        float b = bias[c];
        float4 top, bot;
        float* tp = (float*)&top;
        float* bp = (float*)&bot;
#pragma unroll
        for (int q = 0; q < 4; ++q) {
            float vt = (accT[c][q] + b) * aTp[q];
            float vb = (accB[c][q] + b) * aBp[q];
            if (LEAKY) { vt = leakyf(vt); vb = leakyf(vb); }
            tp[q] = vt; bp[q] = vb;
        }
        size_t ob = (((size_t)n * COFULL + c) * H2 + 2 * iy) * W2 + (ix0 << 1);
        *(float4*)(out + ob) = top;
        *(float4*)(out + ob + W2) = bot;
    }
}

// ---------------- decoder layer 3 (COUT=1): 4-wide quads, float4 loads, fused valid ----------------
// One thread = input pixels (iy, 4tx..4tx+3) => output 2x8 strip at (2iy, 8tx).
__global__ __launch_bounds__(256) void convT_L3_k(
        const float* __restrict__ in, const float* __restrict__ w,
        const float* __restrict__ bias, const float* __restrict__ attn,
        float* __restrict__ out, int* __restrict__ validFlag) {
    const int H = 128, W = 128, CIN = 8;
    int idx = blockIdx.x * 256 + threadIdx.x;   // exact grid: 256*128*32 threads
    int tx = idx & 31;
    int iy = (idx >> 5) & 127;
    int n = idx >> 12;                           // 4096 threads per n (16 blocks)
    int ix0 = tx << 2;
    bool okx = (tx < 31);
    bool oky = (iy + 1 < H);

    float acc[4][4];
#pragma unroll
    for (int q = 0; q < 4; ++q) {
        acc[q][0] = 0.f; acc[q][1] = 0.f; acc[q][2] = 0.f; acc[q][3] = 0.f;
    }

    const float* p = in + ((size_t)n * CIN * H + iy) * W + ix0;
#pragma unroll
    for (int ci = 0; ci < CIN; ++ci) {
        float4 a = *(const float4*)p;
        float a4 = okx ? p[4] : 0.f;
        float av[5] = {a.x, a.y, a.z, a.w, a4};
        float bv[5];
        if (oky) {
            float4 b = *(const float4*)(p + W);
            bv[0] = b.x; bv[1] = b.y; bv[2] = b.z; bv[3] = b.w;
            bv[4] = okx ? p[W + 4] : 0.f;
        } else {
            bv[0] = 0.f; bv[1] = 0.f; bv[2] = 0.f; bv[3] = 0.f; bv[4] = 0.f;
        }
        const float* qw = w + ci * 9;   // wave-uniform -> SGPR
        float w0 = qw[0], w1 = qw[1], w2 = qw[2], w3 = qw[3], w4 = qw[4],
              w5 = qw[5], w6 = qw[6], w7 = qw[7], w8 = qw[8];
#pragma unroll
        for (int q = 0; q < 4; ++q) {
            acc[q][0] += w4 * av[q];
            acc[q][1] += w3 * av[q + 1] + w5 * av[q];
            acc[q][2] += w1 * bv[q] + w7 * av[q];
            acc[q][3] += w0 * bv[q + 1] + w2 * bv[q] + w6 * av[q + 1] + w8 * av[q];
        }
        p += H * W;
    }

    const int W2 = 256;
    size_t abase = ((size_t)n * 256 + 2 * iy) * W2 + (ix0 << 1);   // 32B aligned
    float4 aT0 = *(const float4*)(attn + abase);
    float4 aT1 = *(const float4*)(attn + abase + 4);
    float4 aB0 = *(const float4*)(attn + abase + W2);
    float4 aB1 = *(const float4*)(attn + abase + W2 + 4);
    float bs = bias[0];

    float4 top0, top1, bot0, bot1;
    top0.x = (acc[0][0] + bs) * aT0.x;
    top0.y = (acc[0][1] + bs) * aT0.y;
    top0.z = (acc[1][0] + bs) * aT0.z;
    top0.w = (acc[1][1] + bs) * aT0.w;
    top1.x = (acc[2][0] + bs) * aT1.x;
    top1.y = (acc[2][1] + bs) * aT1.y;
    top1.z = (acc[3][0] + bs) * aT1.z;
    top1.w = (acc[3][1] + bs) * aT1.w;
    bot0.x = (acc[0][2] + bs) * aB0.x;
    bot0.y = (acc[0][3] + bs) * aB0.y;
    bot0.z = (acc[1][2] + bs) * aB0.z;
    bot0.w = (acc[1][3] + bs) * aB0.w;
    bot1.x = (acc[2][2] + bs) * aB1.x;
    bot1.y = (acc[2][3] + bs) * aB1.y;
    bot1.z = (acc[3][2] + bs) * aB1.z;
    bot1.w = (acc[3][3] + bs) * aB1.w;

    *(float4*)(out + abase) = top0;
    *(float4*)(out + abase + 4) = top1;
    *(float4*)(out + abase + W2) = bot0;
    *(float4*)(out + abase + W2 + 4) = bot1;

    float vmax = fmaxf(
        fmaxf(fmaxf(fmaxf(top0.x, top0.y), fmaxf(top0.z, top0.w)),
              fmaxf(fmaxf(top1.x, top1.y), fmaxf(top1.z, top1.w))),
        fmaxf(fmaxf(fmaxf(bot0.x, bot0.y), fmaxf(bot0.z, bot0.w)),
              fmaxf(fmaxf(bot1.x, bot1.y), fmaxf(bot1.z, bot1.w))));
    __shared__ float smax[256];
    int t = threadIdx.x;
    smax[t] = vmax;
    __syncthreads();
    for (int o = 128; o > 0; o >>= 1) {
        if (t < o) smax[t] = fmaxf(smax[t], smax[t + o]);
        __syncthreads();
    }
    if (t == 0 && smax[0] > 1.f) atomicOr(&validFlag[n], 1);
}

// ---------------- decode valid flags ----------------
__global__ void valid_decode_k(const int* __restrict__ flags, float* __restrict__ vout) {
    int l = threadIdx.x;
    vout[l] = flags[l] ? 1.f : 0.f;
}

extern "C" void kernel_launch(void* const* d_in, const int* in_sizes, int n_in,
                              void* d_out, int out_size, void* d_ws, size_t ws_size,
                              hipStream_t stream) {
    const float* x1 = (const float*)d_in[0];
    const float* x2 = (const float*)d_in[1];
    const int* pts = (const int*)d_in[2];
    const float* ew[4] = {(const float*)d_in[3], (const float*)d_in[5], (const float*)d_in[7], (const float*)d_in[9]};
    const float* eb[4] = {(const float*)d_in[4], (const float*)d_in[6], (const float*)d_in[8], (const float*)d_in[10]};
    const float* dw[4] = {(const float*)d_in[11], (const float*)d_in[13], (const float*)d_in[15], (const float*)d_in[17]};
    const float* db[4] = {(const float*)d_in[12], (const float*)d_in[14], (const float*)d_in[16], (const float*)d_in[18]};

    float* ws = (float*)d_ws;
    float* h1a = ws;                    // 524288
    float* h2a = h1a + 524288;          // 524288
    float* Q   = h2a + 524288;          // 16384
    float* t0  = Q + 16384;             // 32768
    float* attn3 = t0 + 32768;          // 262144   (32x32 * 256)
    float* attn2 = attn3 + 262144;      // 1048576  (64x64 * 256)
    float* attn1 = attn2 + 1048576;     // 4194304  (128x128 * 256)
    float* attn0 = attn1 + 4194304;     // 16777216 (256x256 * 256)
    float* bufD1 = attn0 + 16777216;    // 33554432
    float* wT0 = bufD1 + 33554432;      // 216
    float* wT1 = wT0 + 216;             // 3200
    float* wT2 = wT1 + 3200;            // 25088
    float* wT3 = wT2 + 25088;           // 165888
    int* validFlag = (int*)(wT3 + 165888);  // 256 ints
    float* wtd1 = (float*)(validFlag + 256);  // 32*16*9 = 4608
    float* wtd2 = wtd1 + 4608;                // 16*8*9 = 1152
    float* h2a0 = wtd2 + 1152;                // 524288 (dedicated lv0 h2 for deferred attn)
    float* Q0   = h2a0 + 524288;              // 2048   (8*256)
    // pad buffers alias the FRONT of bufD1 (dead until decoder)
    float* pad0 = bufD1;                // 2*3*264*264  = 418176
    float* pad1 = pad0 + 418176;        // 2*8*136*136  = 295936
    float* pad2 = pad1 + 295936;        // 2*16*72*72   = 165888
    float* pad3 = pad2 + 165888;        // 2*32*40*40   = 102400
    float* pad4 = pad3 + 102400;        // 2*64*24*24   = 73728   (total 1056128)
    // partial buffer aliases bufD1 AFTER the pads (also dead until decoder;
    // b1 split partials also live here, consumed by reduce_b1 before bcast_mul overwrites bufD1)
    float* partialBuf = bufD1 + 1056768;   // 16B-aligned; ends well inside bufD1
    float* attnArr[4] = {attn0, attn1, attn2, attn3};

    float* conf = (float*)d_out;            // 16777216
    float* validOut = conf + 16777216;      // 256

    // zero pad borders (whole pad region) + valid flags each call
    hipMemsetAsync(pad0, 0, (size_t)1056128 * 4, stream);
    hipMemsetAsync(validFlag, 0, 256 * 4, stream);

    // weight pre-transpose (tiny)
    wtrans_k<<<(216 + 255) / 256, 256, 0, stream>>>(ew[0], wT0, 3, 8, 9);
    wtrans_k<<<(3200 + 255) / 256, 256, 0, stream>>>(ew[1], wT1, 8, 16, 25);
    wtrans_k<<<(25088 + 255) / 256, 256, 0, stream>>>(ew[2], wT2, 16, 32, 49);
    wtrans_k<<<(165888 + 255) / 256, 256, 0, stream>>>(ew[3], wT3, 32, 64, 81);
    wtransD_k<<<(4608 + 255) / 256, 256, 0, stream>>>(dw[1], wtd1, 32, 16);
    wtransD_k<<<(1152 + 255) / 256, 256, 0, stream>>>(dw[2], wtd2, 16, 8);

    // stage level-0 inputs into padded layout
    pad_in_k<<<(2 * 3 * 65536) / 256, 256, 0, stream>>>(x1, x2, pad0, 3, 256, 256);

    const int Hs[4] = {256, 128, 64, 32};
    const int Couts[4] = {8, 16, 32, 64};
    float* padIn[4] = {pad0, pad1, pad2, pad3};
    float* padOut[4] = {pad1, pad2, pad3, pad4};
    const int padOutImgStride[4] = {8 * 136 * 136, 16 * 72 * 72, 32 * 40 * 40, 64 * 24 * 24};

    for (int lv = 0; lv < 4; ++lv) {
        int Hc = Hs[lv], HW = Hc * Hc;
        float* h2dst = (lv == 0) ? h2a0 : h2a;   // lv0 h2 kept alive for deferred attn
        if (lv == 0) {
            dim3 grid(HW / 4 / 256, 2 * 1, 2);   // (64, 2, 2)
            conv_enc_tile_k<3, 8, 3, 1><<<grid, 256, 0, stream>>>(
                padIn[0], wT0, eb[0], h1a, h2dst, partialBuf, Hc, Hc);
        } else if (lv == 1) {
            dim3 grid(HW / 4 / 256, 4 * 8, 2);   // (16, 32, 2) = 1024 blocks
            conv_enc_tile_k<8, 16, 5, 8><<<grid, 256, 0, stream>>>(
                padIn[1], wT1, eb[1], h1a, h2a, partialBuf, Hc, Hc);
            reduce4_k<8><<<(2 * 16 * HW / 4) / 256, 256, 0, stream>>>(
                (const float4*)partialBuf, eb[1], h1a, h2a, 16, HW);
        } else if (lv == 2) {
            dim3 grid(HW / 4 / 256, 8 * 16, 2);  // (4, 128, 2) = 1024 blocks
            conv_enc_tile_k<16, 32, 7, 16><<<grid, 256, 0, stream>>>(
                padIn[2], wT2, eb[2], h1a, h2a, partialBuf, Hc, Hc);
            reduce4_k<16><<<(2 * 32 * HW / 4) / 256, 256, 0, stream>>>(
                (const float4*)partialBuf, eb[2], h1a, h2a, 32, HW);
        } else {
            dim3 grid(HW / 4 / 256, 16 * 32, 2); // (1, 512, 2) = 1024 blocks
            conv_enc_tile_k<32, 64, 9, 32><<<grid, 256, 0, stream>>>(
                padIn[3], wT3, eb[3], h1a, h2a, partialBuf, Hc, Hc);
            reduce4_k<32><<<(2 * 64 * HW / 4) / 256, 256, 0, stream>>>(
                (const float4*)partialBuf, eb[3], h1a, h2a, 64, HW);
        }
        gatherQ_k<<<(Couts[lv] * 256 + 255) / 256, 256, 0, stream>>>(
            h1a, pts, (lv == 0) ? Q0 : Q, Couts[lv], Hc, lv);
        // attention: lv0 DEFERRED to just before L3
        if (lv == 1)
            attn_fused_k<16, 64, 1024, 4><<<256, 1024, 0, stream>>>(h2a, Q, attnArr[1], HW);
        else if (lv == 2)
            attn_fused_k<32, 16, 1024, 1><<<256, 1024, 0, stream>>>(h2a, Q, attnArr[2], HW);
        else if (lv == 3)
            attn_fused_k<64, 4, 256, 1><<<256, 256, 0, stream>>>(h2a, Q, attnArr[3], HW);
        int npool = Couts[lv] * (HW / 4);
        maxpool_pad_k<<<npool / 256, 256, 0, stream>>>(h1a, padOut[lv], Couts[lv], Hc, Hc);
        maxpool_pad_k<<<npool / 256, 256, 0, stream>>>(h2dst, padOut[lv] + padOutImgStride[lv],
                                                       Couts[lv], Hc, Hc);
    }
    // pad4 img1 section now holds padded encoder output of image 2 (64,16,16)

    // decoder layer 0: split-K convT at batch 1 (16 splits -> 2048 blocks), then reduce+bias
    convT_b1_split_k<16><<<(16 * 32768) / 256, 256, 0, stream>>>(
        pad4 + padOutImgStride[3], dw[0], partialBuf);
    reduce_b1_k<16><<<32768 / 256, 256, 0, stream>>>(partialBuf, db[0], t0);
    // broadcast*attn3 + leaky -> bufD1 (256,32,32,32)
    {
        size_t tot = (size_t)256 * 32 * 1024;
        bcast_mul_leaky_k<<<(unsigned)((tot + 255) / 256), 256, 0, stream>>>(t0, attn3, bufD1, 32, 1024);
    }
    // layer 1: (256,32,32,32) -> (256,16,64,64) * attn2, leaky -> conf (staging)
    {
        int tot = 256 * 32 * 32;   // 1024 blocks per dispatch
        for (int s = 0; s < 4; ++s) {
            convT_quadV_k<32, 16, true><<<tot / 256, 256, 0, stream>>>(
                bufD1, wtd1 + s * 4, db[1] + s * 4, attn2,
                conf + (size_t)(s * 4) * 64 * 64, 32, 32);
        }
    }
    // layer 2: (256,16,64,64) -> (256,8,128,128) * attn1, leaky -> bufD1
    {
        int tot = 256 * 64 * 32;   // 2048 blocks per dispatch
        for (int s = 0; s < 2; ++s) {
            convT_quadV2_k<16, 8, true><<<tot / 256, 256, 0, stream>>>(
                conf, wtd2 + s * 4, db[2] + s * 4, attn1,
                bufD1 + (size_t)(s * 4) * 128 * 128, 64, 64);
        }
    }
    // DEFERRED level-0 attention: attn0 computed just before its consumer
    attn_fused_k<8, 256, 1024, 16><<<256, 1024, 0, stream>>>(h2a0, Q0, attn0, 65536);
    // layer 3: (256,8,128,128) -> (256,1,256,256) * attn0, no leaky -> conf, fused valid (4-wide)
    {
        int tot = 256 * 128 * 32;   // 4096 blocks
        convT_L3_k<<<tot / 256, 256, 0, stream>>>(
            bufD1, dw[3], db[3], attn0, conf, validFlag);
    }
    valid_decode_k<<<1, 256, 0, stream>>>(validFlag, validOut);
}